// Round 4
// baseline (144.657 us; speedup 1.0000x reference)
//
#include <hip/hip_runtime.h>

#define NEG_INF (-__builtin_inff())

typedef _Float16 h2v __attribute__((ext_vector_type(2)));   // arithmetic type
typedef __fp16   h2r __attribute__((ext_vector_type(2)));   // cvt_pkrtz return type

union H2U { h2v h; h2r r; unsigned int u; };

static __device__ __forceinline__ unsigned int pk(float a, float b) {
    H2U c; c.r = __builtin_amdgcn_cvt_pkrtz(a, b); return c.u;
}
static __device__ __forceinline__ h2v u2h(unsigned int u) {
    H2U c; c.u = u; return c.h;
}

// Pack weights fp32 -> broadcast half2, transposed to [ci][kh][co][kw] so the
// main kernel's per-(ci,kh) slab of 40 dwords is contiguous + wave-uniform.
__global__ void prep_weights(const float* __restrict__ w, unsigned int* __restrict__ wpk) {
    int i = threadIdx.x + blockIdx.x * 256;
    if (i >= 800) return;
    int kw = i % 5; int r = i / 5;
    int co = r % 8; r /= 8;
    int kh = r % 5; int ci = r / 5;
    float v = w[((co * 4 + ci) * 5 + kh) * 5 + kw];
    wpk[i] = pk(v, v);
}

// Each thread: all Co=8 outputs for 8 consecutive w pixels at one (n,h),
// packed-fp16 math (2 pixels per v_pk_* instruction).
// Block = 256 = 4 rows x 64 w-groups (one full row per wave64 -> uniform
// row-edge branches). Grid = 8n * 512h / 4 = 1024 blocks.
__global__ __launch_bounds__(256) void dil2d_kernel(const float* __restrict__ x,
                                                    const unsigned int* __restrict__ wpk,
                                                    float* __restrict__ out) {
    const int Ci = 4, H = 512, W = 512;

    const int tid = threadIdx.x;
    const int wg  = tid & 63;         // w-group 0..63
    const int w0  = wg << 3;          // 0..504
    const int b   = blockIdx.x;
    const int n   = b >> 7;
    const int h   = ((b & 127) << 2) + (tid >> 6);

    const bool left  = (w0 == 0);
    const bool right = (w0 == 504);
    const float NI = NEG_INF;

    h2v acc[8][4];
#pragma unroll
    for (int co = 0; co < 8; ++co)
#pragma unroll
        for (int p = 0; p < 4; ++p) acc[co][p] = u2h(0xFC00FC00u);  // {-inf,-inf}

    const float* xn = x + n * (Ci * H * W);

    for (int ci = 0; ci < Ci; ++ci) {
        const float* xc = xn + ci * (H * W);
        for (int kh = 0; kh < 5; ++kh) {
            const int r = h + kh - 2;
            if (r < 0 || r >= H) continue;           // wave-uniform
            const float* xr = xc + r * W + w0;

            // window x[w0-2 .. w0+9] -> even packs P0..P5, odd packs Q0..Q4
            const float2 lo = *(const float2*)(xr + (left ? 0 : -2));
            const float4 m1 = *(const float4*)(xr);
            const float4 m2 = *(const float4*)(xr + 4);
            const float2 hi = *(const float2*)(xr + (right ? 0 : 8));
            const float v0  = left  ? NI : lo.x;
            const float v1  = left  ? NI : lo.y;
            const float v10 = right ? NI : hi.x;
            const float v11 = right ? NI : hi.y;

            unsigned int P0 = pk(v0,   v1);
            unsigned int P1 = pk(m1.x, m1.y);
            unsigned int P2 = pk(m1.z, m1.w);
            unsigned int P3 = pk(m2.x, m2.y);
            unsigned int P4 = pk(m2.z, m2.w);
            unsigned int P5 = pk(v10,  v11);
            unsigned int Q0 = __builtin_amdgcn_alignbit(P1, P0, 16);
            unsigned int Q1 = __builtin_amdgcn_alignbit(P2, P1, 16);
            unsigned int Q2 = __builtin_amdgcn_alignbit(P3, P2, 16);
            unsigned int Q3 = __builtin_amdgcn_alignbit(P4, P3, 16);
            unsigned int Q4 = __builtin_amdgcn_alignbit(P5, P4, 16);

            const unsigned int T[5][4] = {
                {P0, P1, P2, P3},   // kw=0, offset -2
                {Q0, Q1, Q2, Q3},   // kw=1, offset -1
                {P1, P2, P3, P4},   // kw=2, offset  0
                {Q1, Q2, Q3, Q4},   // kw=3, offset +1
                {P2, P3, P4, P5},   // kw=4, offset +2
            };

            const unsigned int* wrow = wpk + (ci * 5 + kh) * 40;  // uniform -> s_load
#pragma unroll
            for (int co = 0; co < 8; ++co) {
#pragma unroll
                for (int kw = 0; kw < 5; ++kw) {
                    const h2v wv = u2h(wrow[co * 5 + kw]);
#pragma unroll
                    for (int p = 0; p < 4; ++p) {
                        acc[co][p] = __builtin_elementwise_max(acc[co][p],
                                                               (h2v)(u2h(T[kw][p]) + wv));
                    }
                }
            }
        }
    }

#pragma unroll
    for (int co = 0; co < 8; ++co) {
        float* on = out + ((size_t)(n * 8 + co) * H + h) * W + w0;
        float4 o1, o2;
        o1.x = (float)acc[co][0][0]; o1.y = (float)acc[co][0][1];
        o1.z = (float)acc[co][1][0]; o1.w = (float)acc[co][1][1];
        o2.x = (float)acc[co][2][0]; o2.y = (float)acc[co][2][1];
        o2.z = (float)acc[co][3][0]; o2.w = (float)acc[co][3][1];
        *(float4*)(on)     = o1;
        *(float4*)(on + 4) = o2;
    }
}

extern "C" void kernel_launch(void* const* d_in, const int* in_sizes, int n_in,
                              void* d_out, int out_size, void* d_ws, size_t ws_size,
                              hipStream_t stream) {
    const float* x = (const float*)d_in[0];
    const float* w = (const float*)d_in[1];
    float* out     = (float*)d_out;
    unsigned int* wpk = (unsigned int*)d_ws;   // 800 dwords = 3.2 KB

    hipLaunchKernelGGL(prep_weights, dim3(4), dim3(256), 0, stream, w, wpk);
    hipLaunchKernelGGL(dil2d_kernel, dim3(1024), dim3(256), 0, stream, x, wpk, out);
}

// Round 5
// 140.699 us; speedup vs baseline: 1.0281x; 1.0281x over previous
//
#include <hip/hip_runtime.h>

#define NEG_INF (-__builtin_inff())

typedef _Float16 h2v __attribute__((ext_vector_type(2)));   // arithmetic type
typedef __fp16   h2r __attribute__((ext_vector_type(2)));   // cvt_pkrtz return type

union H2U { h2v h; h2r r; unsigned int u; };

static __device__ __forceinline__ unsigned int pk(float a, float b) {
    H2U c; c.r = __builtin_amdgcn_cvt_pkrtz(a, b); return c.u;
}
static __device__ __forceinline__ h2v u2h(unsigned int u) {
    H2U c; c.u = u; return c.h;
}

// Pack weights fp32 -> broadcast half2, transposed to [ci][kh][co][kw] so the
// main kernel's per-(ci,kh) slab of 40 dwords is contiguous + wave-uniform.
__global__ void prep_weights(const float* __restrict__ w, unsigned int* __restrict__ wpk) {
    int i = threadIdx.x + blockIdx.x * 256;
    if (i >= 800) return;
    int kw = i % 5; int r = i / 5;
    int co = r % 8; r /= 8;
    int kh = r % 5; int ci = r / 5;
    float v = w[((co * 4 + ci) * 5 + kh) * 5 + kw];
    wpk[i] = pk(v, v);
}

// Each thread: all Co=8 outputs for 4 consecutive w pixels at one (n,h),
// packed-fp16 math (2 pixels per v_pk_* instruction).
// Block = 256 = 2 rows x 128 w-groups (each wave64 covers one row -> uniform
// row-edge branches). Grid = 8n * 512h / 2 = 2048 blocks -> 32 waves/CU.
__global__ __launch_bounds__(256) void dil2d_kernel(const float* __restrict__ x,
                                                    const unsigned int* __restrict__ wpk,
                                                    float* __restrict__ out) {
    const int Ci = 4, H = 512, W = 512;

    const int tid = threadIdx.x;
    const int wg  = tid & 127;        // w-group 0..127
    const int w0  = wg << 2;          // 0..508
    const int b   = blockIdx.x;
    const int n   = b >> 8;
    const int h   = ((b & 255) << 1) + (tid >> 7);

    const bool left  = (w0 == 0);
    const bool right = (w0 == 508);
    const float NI = NEG_INF;

    h2v acc[8][2];
#pragma unroll
    for (int co = 0; co < 8; ++co)
#pragma unroll
        for (int p = 0; p < 2; ++p) acc[co][p] = u2h(0xFC00FC00u);  // {-inf,-inf}

    const float* xn = x + n * (Ci * H * W);

    for (int ci = 0; ci < Ci; ++ci) {
        const float* xc = xn + ci * (H * W);
        for (int kh = 0; kh < 5; ++kh) {
            const int r = h + kh - 2;
            if (r < 0 || r >= H) continue;           // wave-uniform
            const float* xr = xc + r * W + w0;

            // window x[w0-2 .. w0+5] -> even packs P0..P3, odd packs Q0..Q2
            const float2 lo = *(const float2*)(xr + (left ? 0 : -2));
            const float4 mid = *(const float4*)(xr);
            const float2 hi = *(const float2*)(xr + (right ? 0 : 4));
            const float v0 = left  ? NI : lo.x;
            const float v1 = left  ? NI : lo.y;
            const float v6 = right ? NI : hi.x;
            const float v7 = right ? NI : hi.y;

            unsigned int P0 = pk(v0,    v1);
            unsigned int P1 = pk(mid.x, mid.y);
            unsigned int P2 = pk(mid.z, mid.w);
            unsigned int P3 = pk(v6,    v7);
            unsigned int Q0 = __builtin_amdgcn_alignbit(P1, P0, 16);
            unsigned int Q1 = __builtin_amdgcn_alignbit(P2, P1, 16);
            unsigned int Q2 = __builtin_amdgcn_alignbit(P3, P2, 16);

            const unsigned int T[5][2] = {
                {P0, P1},   // kw=0, offset -2
                {Q0, Q1},   // kw=1, offset -1
                {P1, P2},   // kw=2, offset  0
                {Q1, Q2},   // kw=3, offset +1
                {P2, P3},   // kw=4, offset +2
            };

            const unsigned int* wrow = wpk + (ci * 5 + kh) * 40;  // uniform -> s_load
#pragma unroll
            for (int co = 0; co < 8; ++co) {
#pragma unroll
                for (int kw = 0; kw < 5; ++kw) {
                    const h2v wv = u2h(wrow[co * 5 + kw]);
#pragma unroll
                    for (int p = 0; p < 2; ++p) {
                        acc[co][p] = __builtin_elementwise_max(acc[co][p],
                                                               (h2v)(u2h(T[kw][p]) + wv));
                    }
                }
            }
        }
    }

#pragma unroll
    for (int co = 0; co < 8; ++co) {
        float* on = out + ((size_t)(n * 8 + co) * H + h) * W + w0;
        float4 o;
        o.x = (float)acc[co][0][0]; o.y = (float)acc[co][0][1];
        o.z = (float)acc[co][1][0]; o.w = (float)acc[co][1][1];
        *(float4*)(on) = o;
    }
}

extern "C" void kernel_launch(void* const* d_in, const int* in_sizes, int n_in,
                              void* d_out, int out_size, void* d_ws, size_t ws_size,
                              hipStream_t stream) {
    const float* x = (const float*)d_in[0];
    const float* w = (const float*)d_in[1];
    float* out     = (float*)d_out;
    unsigned int* wpk = (unsigned int*)d_ws;   // 800 dwords = 3.2 KB

    hipLaunchKernelGGL(prep_weights, dim3(4), dim3(256), 0, stream, w, wpk);
    hipLaunchKernelGGL(dil2d_kernel, dim3(2048), dim3(256), 0, stream, x, wpk, out);
}